// Round 7
// baseline (615.545 us; speedup 1.0000x reference)
//
#include <hip/hip_runtime.h>
#include <math.h>

// out = [N, 2, 128] fp32 : {segment_max[row_ids[n]] - feat[n], feat[n]}
// N = 1e6, D = 128, R = 50000.
//
// Round-7: counting-sort grouping + fused reduce/emit that caches member
// values in REGISTERS (statically-indexed unrolled array) so feat is read
// exactly once. KREG=16 f32x4/lane x 2 members-per-step covers cnt<=32;
// rarer rows fall back to a re-read tail. fmax commutative -> bit-exact.

#define R_ROWS 50000
#define D_DIM  128
#define KREG   16            // covers cnt <= 2*KREG = 32

typedef float f32x4 __attribute__((ext_vector_type(4)));

// ---- ws layout ----
//  hist   : u32 [R] @ 0
//  base   : u32 [R] @ 200,000
//  cursor : u32 [R] @ 400,000
//  perm   : int [N] @ 600,000

__global__ void __launch_bounds__(256)
zero_u32(unsigned int* __restrict__ p, int n) {
    int i = blockIdx.x * blockDim.x + threadIdx.x;
    int stride = gridDim.x * blockDim.x;
    for (; i < n; i += stride) p[i] = 0u;
}

__global__ void __launch_bounds__(256)
hist_count(const int* __restrict__ ids, unsigned int* __restrict__ hist, int N) {
    int i = blockIdx.x * blockDim.x + threadIdx.x;
    int stride = gridDim.x * blockDim.x;
    for (; i < N; i += stride) atomicAdd(&hist[ids[i]], 1u);
}

// Single-block exclusive scan of hist[R] -> base, cursor.
__global__ void __launch_bounds__(1024)
scan_block(const unsigned int* __restrict__ hist,
           unsigned int* __restrict__ base,
           unsigned int* __restrict__ cursor) {
    __shared__ unsigned int lds[1024];
    const int t = threadIdx.x;
    const int C = (R_ROWS + 1023) / 1024;   // 49 per thread
    const int j0 = t * C;
    unsigned int tot = 0;
    for (int k = 0; k < C; ++k) {
        int j = j0 + k;
        if (j < R_ROWS) tot += hist[j];
    }
    lds[t] = tot; __syncthreads();
    for (int off = 1; off < 1024; off <<= 1) {
        unsigned int v = (t >= off) ? lds[t - off] : 0u;
        __syncthreads();
        lds[t] += v;
        __syncthreads();
    }
    unsigned int run = (t == 0) ? 0u : lds[t - 1];
    for (int k = 0; k < C; ++k) {
        int j = j0 + k;
        if (j < R_ROWS) {
            base[j] = run;
            cursor[j] = run;
            run += hist[j];
        }
    }
}

__global__ void __launch_bounds__(256)
rank_scatter(const int* __restrict__ ids, unsigned int* __restrict__ cursor,
             int* __restrict__ perm, int N) {
    int i = blockIdx.x * blockDim.x + threadIdx.x;
    int stride = gridDim.x * blockDim.x;
    for (; i < N; i += stride) {
        unsigned int slot = atomicAdd(&cursor[ids[i]], 1u);
        perm[slot] = i;
    }
}

// One wave per segment row; half-waves take even/odd members; f32x4 lanes.
// Members cached in registers (static unroll) -> feat read exactly once for
// cnt<=32. Rare longer rows re-read the tail members.
__global__ void __launch_bounds__(256)
reduce_emit(const float* __restrict__ feat,
            const int* __restrict__ perm,
            const unsigned int* __restrict__ base,
            const unsigned int* __restrict__ hist,
            float* __restrict__ out) {
    int r = blockIdx.x * 4 + (threadIdx.x >> 6);
    if (r >= R_ROWS) return;
    int lane = threadIdx.x & 63;
    int half = lane >> 5;          // member parity this lane handles
    int col4 = lane & 31;          // float4 column within the 128-float row
    unsigned int start = base[r];
    unsigned int cnt = hist[r];
    if (!cnt) return;              // empty segments never gathered

    f32x4 vv[KREG];
    int   nn[KREG];
    f32x4 m = {-INFINITY, -INFINITY, -INFINITY, -INFINITY};

    #pragma unroll
    for (int j = 0; j < KREG; ++j) {
        unsigned int kk = (unsigned)(2 * j + half);
        if (kk < cnt) {
            int n = perm[start + kk];
            f32x4 v = *reinterpret_cast<const f32x4*>(
                feat + (long long)n * D_DIM + (col4 << 2));
            nn[j] = n; vv[j] = v;
            m.x = fmaxf(m.x, v.x); m.y = fmaxf(m.y, v.y);
            m.z = fmaxf(m.z, v.z); m.w = fmaxf(m.w, v.w);
        }
    }
    // overflow tail (cnt > 32): rare, contributes to max only
    for (unsigned int kk = 2 * KREG + half; kk < cnt; kk += 2) {
        int n = perm[start + kk];
        f32x4 v = *reinterpret_cast<const f32x4*>(
            feat + (long long)n * D_DIM + (col4 << 2));
        m.x = fmaxf(m.x, v.x); m.y = fmaxf(m.y, v.y);
        m.z = fmaxf(m.z, v.z); m.w = fmaxf(m.w, v.w);
    }

    // combine the two half-wave partial maxima (same column, lane ^ 32)
    m.x = fmaxf(m.x, __shfl_xor(m.x, 32));
    m.y = fmaxf(m.y, __shfl_xor(m.y, 32));
    m.z = fmaxf(m.z, __shfl_xor(m.z, 32));
    m.w = fmaxf(m.w, __shfl_xor(m.w, 32));

    #pragma unroll
    for (int j = 0; j < KREG; ++j) {
        unsigned int kk = (unsigned)(2 * j + half);
        if (kk < cnt) {
            f32x4 v = vv[j];
            f32x4 res = m - v;
            f32x4* o = reinterpret_cast<f32x4*>(out + (long long)nn[j] * 2 * D_DIM);
            __builtin_nontemporal_store(res, o + col4);        // [n][0][:]
            __builtin_nontemporal_store(v,   o + 32 + col4);   // [n][1][:]
        }
    }
    // overflow tail: re-read members beyond the register window
    for (unsigned int kk = 2 * KREG + half; kk < cnt; kk += 2) {
        int n = perm[start + kk];
        f32x4 v = *reinterpret_cast<const f32x4*>(
            feat + (long long)n * D_DIM + (col4 << 2));        // L2 hit likely
        f32x4 res = m - v;
        f32x4* o = reinterpret_cast<f32x4*>(out + (long long)n * 2 * D_DIM);
        __builtin_nontemporal_store(res, o + col4);
        __builtin_nontemporal_store(v,   o + 32 + col4);
    }
}

extern "C" void kernel_launch(void* const* d_in, const int* in_sizes, int n_in,
                              void* d_out, int out_size, void* d_ws, size_t ws_size,
                              hipStream_t stream) {
    const float* feat = (const float*)d_in[0];
    const int*   ids  = (const int*)d_in[1];
    const int N = in_sizes[0] / D_DIM;

    char* ws = (char*)d_ws;
    unsigned int* hist   = (unsigned int*)(ws + 0);
    unsigned int* basep  = (unsigned int*)(ws + 200000);
    unsigned int* cursor = (unsigned int*)(ws + 400000);
    int*          perm   = (int*)(ws + 600000);

    const int block = 256;

    zero_u32<<<128, block, 0, stream>>>(hist, R_ROWS);
    hist_count<<<2048, block, 0, stream>>>(ids, hist, N);
    scan_block<<<1, 1024, 0, stream>>>(hist, basep, cursor);
    rank_scatter<<<2048, block, 0, stream>>>(ids, cursor, perm, N);
    reduce_emit<<<(R_ROWS + 3) / 4, block, 0, stream>>>(
        feat, perm, basep, hist, (float*)d_out);
}